// Round 1
// baseline (1795.783 us; speedup 1.0000x reference)
//
#include <hip/hip_runtime.h>
#include <hip/hip_bf16.h>

// ---------------------------------------------------------------------------
// QuestionGuidedGraphAttention on MI355X — v2
//
// att_n = segsoftmax( tanh(nodes@W_n + (question@W_nq + b_nq + b_n)[gid]) @ w_nv + b_nv )
// att_e = same for edges.
//
// v2 changes vs v1 (1349 us):
//  - BM 32 -> 64, 512 threads / 8 waves; wave w owns 64-col slice x 64 rows
//    (acc[4][4] per thread, same reg count as v1's acc[2][8]).
//    Halves per-row B-restage cost and block count.
//  - Bt stored k-window-tiled [k0/32][p][32] so each k-step's 32KB B window is
//    contiguous; staging = 4 coalesced uint4 loads/thread.
//  - Register-prefetch software pipeline: B(t+1) and A(t+2) issued into regs
//    before the frag-read+MFMA phase, written to LDS after the second barrier.
//    Global-load latency hides under compute (reg loads survive s_barrier).
// ---------------------------------------------------------------------------

typedef __attribute__((ext_vector_type(4))) float  floatx4;
typedef __attribute__((ext_vector_type(8))) short  shortx8;

#define TN_CONST 131072
#define TE_CONST 262144
#define BM 64
#define BK 32
#define NSTEP 16   // 512 / BK

__device__ __forceinline__ unsigned short f2bf(float f) {
    union { float f; unsigned u; } v; v.f = f;
    unsigned u = v.u;
    unsigned r = (u + 0x7FFFu + ((u >> 16) & 1u)) >> 16;   // RNE
    return (unsigned short)r;
}

// --- W transpose + bf16 convert, k-window tiled --------------------------
// Wt[(k>>5)][p][k&31] = bf16(W[k][p])   (each 32-k window contiguous: 512*32)
__global__ void prep_wt_kernel(const float* __restrict__ Wn, const float* __restrict__ We,
                               unsigned short* __restrict__ Wtn, unsigned short* __restrict__ Wte)
{
    int c = blockIdx.x * 256 + threadIdx.x;      // 0 .. 2*262144-1
    const int sel = c >> 18;
    const int idx = c & 262143;
    const int p = idx >> 9, k = idx & 511;
    const float* W = sel ? We : Wn;
    unsigned short* Wt = sel ? Wte : Wtn;
    Wt[((k >> 5) << 14) + (p << 5) + (k & 31)] = f2bf(W[(size_t)k * 512 + p]);
}

// --- Qp[b][p] = sum_k question[b][k]*Wq[k][p] + bq[p] + bh[p]  (atomic k-split)
__global__ void prep_q_kernel(const float* __restrict__ question,
                              const float* __restrict__ Wnq, const float* __restrict__ bnq,
                              const float* __restrict__ bn,
                              const float* __restrict__ Weq, const float* __restrict__ beq,
                              const float* __restrict__ be,
                              float* __restrict__ Qpn, float* __restrict__ Qpe)
{
    const int b     = blockIdx.x;    // 0..63
    const int which = blockIdx.y;    // 0=n 1=e
    const int kc    = blockIdx.z;    // 0..3 (chunks of 192)
    const int p     = threadIdx.x;   // 0..511
    const float* W  = which ? Weq : Wnq;
    const float* bq = which ? beq : bnq;
    const float* bh = which ? be  : bn;
    float* Qp       = which ? Qpe : Qpn;
    const float* q  = question + b * 768;
    float s = 0.f;
    const int kbeg = kc * 192, kend = kbeg + 192;
    for (int k = kbeg; k < kend; ++k) s += q[k] * W[(size_t)k * 512 + p];
    if (kc == 0) s += bq[p] + bh[p];
    atomicAdd(&Qp[b * 512 + p], s);
}

// --- main fused kernel -------------------------------------------------------
// grid.x = M/64 blocks, 512 threads (8 waves). Block: rows r0..r0+63, all 512
// cols. Wave w owns cols [w*64, w*64+64) for all 64 rows -> acc[4][4] frags.
__global__ __launch_bounds__(512, 2)
void fused_gemm_attn(const float* __restrict__ A,          // [M][512] fp32
                     const unsigned short* __restrict__ Bt, // [16][512][32] bf16 tiled
                     const float* __restrict__ Qp,          // [64][512] fp32 (biases folded)
                     const float* __restrict__ wv,          // [512]
                     const float* __restrict__ bvp,         // scalar
                     const int*   __restrict__ gid,         // [M]
                     float* __restrict__ eout,              // [M]  exp(s) out
                     float* __restrict__ zglob)             // [64] segment sums
{
    __shared__ unsigned short As[BM][BK + 8];     // 64x40  (stride 80B: 2-way banks, free)
    __shared__ unsigned short Bs[512][BK + 8];    // 512x40
    __shared__ float sred[8][BM];
    __shared__ float zpart[64];
    __shared__ int   gsh[64];

    const int tid  = threadIdx.x;
    const int wave = tid >> 6;
    const int lane = tid & 63;
    const int m16  = lane & 15;
    const int q4   = lane >> 4;
    const long r0  = (long)blockIdx.x * BM;

    floatx4 acc[4][4];
#pragma unroll
    for (int i = 0; i < 4; ++i)
#pragma unroll
        for (int j = 0; j < 4; ++j) acc[i][j] = (floatx4){0.f, 0.f, 0.f, 0.f};

    // A staging: 64x32 fp32 = 512 float4 chunks, one per thread
    const int ar  = tid >> 3;          // row 0..63
    const int akc = (tid & 7) << 2;    // k offset 0,4,..28
    const float* aptr = A + (size_t)(r0 + ar) * 512 + akc;
    // B staging: 512x32 bf16 window contiguous; 4 uint4 chunks per thread
    const unsigned short* bptr = Bt + (size_t)tid * 8;

    float4 apf[2];
    uint4  bpf[4];

    // ---- prologue: load step 0 (+ A step 1), write step 0 to LDS ----
    apf[0] = *(const float4*)(aptr);
#pragma unroll
    for (int i = 0; i < 4; ++i)
        bpf[i] = *(const uint4*)(bptr + i * 4096);
    apf[1] = *(const float4*)(aptr + BK);
    {
        const float4 v = apf[0];
        unsigned lo = ((unsigned)f2bf(v.y) << 16) | f2bf(v.x);
        unsigned hi = ((unsigned)f2bf(v.w) << 16) | f2bf(v.z);
        *(uint2*)&As[ar][akc] = make_uint2(lo, hi);
#pragma unroll
        for (int i = 0; i < 4; ++i) {
            const int c = tid + i * 512;
            *(uint4*)&Bs[c >> 2][(c & 3) << 3] = bpf[i];
        }
    }

#pragma unroll
    for (int t = 0; t < NSTEP; ++t) {
        __syncthreads();                       // step-t LDS visible
        // issue next-step global loads (reg-destined: survive the barrier)
        if (t + 1 < NSTEP) {
#pragma unroll
            for (int i = 0; i < 4; ++i)
                bpf[i] = *(const uint4*)(bptr + (size_t)(t + 1) * 16384 + i * 4096);
        }
        if (t + 2 < NSTEP)
            apf[t & 1] = *(const float4*)(aptr + (t + 2) * BK);

        shortx8 af[4], bfr[4];
#pragma unroll
        for (int i = 0; i < 4; ++i)
            af[i] = *(const shortx8*)&As[i * 16 + m16][q4 * 8];
#pragma unroll
        for (int j = 0; j < 4; ++j)
            bfr[j] = *(const shortx8*)&Bs[wave * 64 + j * 16 + m16][q4 * 8];
#pragma unroll
        for (int i = 0; i < 4; ++i)
#pragma unroll
            for (int j = 0; j < 4; ++j)
                acc[i][j] = __builtin_amdgcn_mfma_f32_16x16x32_bf16(af[i], bfr[j], acc[i][j], 0, 0, 0);

        if (t + 1 < NSTEP) {
            __syncthreads();                   // all reads of step t done
            const float4 v = apf[(t + 1) & 1];
            unsigned lo = ((unsigned)f2bf(v.y) << 16) | f2bf(v.x);
            unsigned hi = ((unsigned)f2bf(v.w) << 16) | f2bf(v.z);
            *(uint2*)&As[ar][akc] = make_uint2(lo, hi);
#pragma unroll
            for (int i = 0; i < 4; ++i) {
                const int c = tid + i * 512;
                *(uint4*)&Bs[c >> 2][(c & 3) << 3] = bpf[i];
            }
        }
    }

    // ---- epilogue: s[row] = sum_p tanh(h + Qp[g][p]) * wv[p] ----
    // C/D layout: col = lane&15, row = (lane>>4)*4 + reg   [verified m89/m91]
    if (tid < 64) { gsh[tid] = gid[r0 + tid]; zpart[tid] = 0.f; }
    __syncthreads();

    const float bv = bvp[0];
    float wvp[4];
#pragma unroll
    for (int j = 0; j < 4; ++j) wvp[j] = wv[wave * 64 + j * 16 + m16];

#pragma unroll
    for (int i = 0; i < 4; ++i) {
#pragma unroll
        for (int reg = 0; reg < 4; ++reg) {
            const int row = i * 16 + q4 * 4 + reg;
            const int g   = gsh[row];
            const float* qrow = Qp + (size_t)g * 512 + wave * 64 + m16;
            float partial = 0.f;
#pragma unroll
            for (int j = 0; j < 4; ++j) {
                float h  = acc[i][j][reg] + qrow[j * 16];
                float ex = __expf(2.f * h);                                // tanh
                float tt = (ex - 1.f) * __builtin_amdgcn_rcpf(ex + 1.f);
                partial += tt * wvp[j];
            }
            partial += __shfl_xor(partial, 1);
            partial += __shfl_xor(partial, 2);
            partial += __shfl_xor(partial, 4);
            partial += __shfl_xor(partial, 8);
            if (m16 == 0) sred[wave][row] = partial;   // per-wave 64-col partial
        }
    }
    __syncthreads();
    if (tid < BM) {
        float s = bv;
#pragma unroll
        for (int w = 0; w < 8; ++w) s += sred[w][tid];
        float e = __expf(s);                       // no max-subtract: |s| small
        eout[r0 + tid] = e;
        atomicAdd(&zpart[gsh[tid]], e);
    }
    __syncthreads();
    if (tid < 64) {
        float v = zpart[tid];
        if (v != 0.f) atomicAdd(&zglob[tid], v);
    }
}

// --- normalize: att = e / z[gid] --------------------------------------------
__global__ void norm_kernel(float* __restrict__ out, const int* __restrict__ ngid,
                            const int* __restrict__ egid, const float* __restrict__ z)
{
    int idx = blockIdx.x * 256 + threadIdx.x;     // 0..393215
    float zz;
    if (idx < TN_CONST) zz = z[ngid[idx]];
    else                zz = z[64 + egid[idx - TN_CONST]];
    out[idx] = out[idx] / zz;
}

extern "C" void kernel_launch(void* const* d_in, const int* in_sizes, int n_in,
                              void* d_out, int out_size, void* d_ws, size_t ws_size,
                              hipStream_t stream)
{
    const float* question = (const float*)d_in[0];
    const float* nodes    = (const float*)d_in[1];
    const float* edges    = (const float*)d_in[2];
    const float* W_nq     = (const float*)d_in[3];
    const float* b_nq     = (const float*)d_in[4];
    const float* W_n      = (const float*)d_in[5];
    const float* b_n      = (const float*)d_in[6];
    const float* w_nv     = (const float*)d_in[7];
    const float* b_nv     = (const float*)d_in[8];
    const float* W_eq     = (const float*)d_in[9];
    const float* b_eq     = (const float*)d_in[10];
    const float* W_e      = (const float*)d_in[11];
    const float* b_e      = (const float*)d_in[12];
    const float* w_ev     = (const float*)d_in[13];
    const float* b_ev     = (const float*)d_in[14];
    const int* node_gid   = (const int*)d_in[15];
    const int* edge_gid   = (const int*)d_in[16];
    float* out = (float*)d_out;

    // workspace layout (bytes):
    //   [0,512)              z[128]
    //   [512,131584)         Qpn [64*512] f32
    //   [131584,262656)      Qpe [64*512] f32
    //   [262656,786944)      Wtn [512*512] bf16 (tiled)
    //   [786944,1311232)     Wte [512*512] bf16 (tiled)
    char* ws = (char*)d_ws;
    float*          z   = (float*)(ws);
    float*          Qpn = (float*)(ws + 512);
    float*          Qpe = (float*)(ws + 131584);
    unsigned short* Wtn = (unsigned short*)(ws + 262656);
    unsigned short* Wte = (unsigned short*)(ws + 786944);

    hipMemsetAsync(ws, 0, 262656, stream);  // z + Qpn + Qpe

    prep_wt_kernel<<<2048, 256, 0, stream>>>(W_n, W_e, Wtn, Wte);
    prep_q_kernel<<<dim3(64, 2, 4), 512, 0, stream>>>(question, W_nq, b_nq, b_n,
                                                      W_eq, b_eq, b_e, Qpn, Qpe);
    fused_gemm_attn<<<TN_CONST / BM, 512, 0, stream>>>(nodes, Wtn, Qpn, w_nv, b_nv,
                                                       node_gid, out, z);
    fused_gemm_attn<<<TE_CONST / BM, 512, 0, stream>>>(edges, Wte, Qpe, w_ev, b_ev,
                                                       edge_gid, out + TN_CONST, z + 64);
    norm_kernel<<<1536, 256, 0, stream>>>(out, node_gid, edge_gid, z);
}

// Round 2
// 1263.625 us; speedup vs baseline: 1.4211x; 1.4211x over previous
//
#include <hip/hip_runtime.h>
#include <hip/hip_bf16.h>

// ---------------------------------------------------------------------------
// QuestionGuidedGraphAttention on MI355X — v3
//
// att_n = segsoftmax( tanh(nodes@W_n + (question@W_nq + b_nq + b_n)[gid]) @ w_nv + b_nv )
// att_e = same for edges.
//
// v3 changes vs v2 (1796 us; v1 1349 us):
//  - v2's register prefetch spilled (WRITE_SIZE 165 MB of scratch traffic).
//    All staging now goes through __builtin_amdgcn_global_load_lds (DMA,
//    zero VGPR cost): B bf16 (k-window tiled, linear LDS) and A fp32.
//  - Counted-vmcnt 2-phase pipeline with raw s_barrier: stage(t+1/t+2) loads
//    stay in flight across barriers while tile t computes (vmcnt(6) steady).
//  - A kept fp32 in LDS; fp32->bf16 conversion at frag-read time.
//    A LDS layout XOR-chunk-swizzled via pre-swizzled GLOBAL source address
//    (DMA dest must be linear) to avoid 16-way bank conflicts on 128B rows.
//  - 8 waves as 2x4 grid (32 rows x 128 cols per wave), acc[2][8] = 64 regs.
//  - __launch_bounds__(512,1): 256-reg budget, no spills. ~100KB LDS, 1 blk/CU.
// ---------------------------------------------------------------------------

typedef __attribute__((ext_vector_type(4))) float  floatx4;
typedef __attribute__((ext_vector_type(8))) short  shortx8;

#define TN_CONST 131072
#define TE_CONST 262144
#define BM 64
#define BK 32
#define NSTEP 16   // 512 / BK

__device__ __forceinline__ unsigned short f2bf(float f) {
    union { float f; unsigned u; } v; v.f = f;
    unsigned u = v.u;
    unsigned r = (u + 0x7FFFu + ((u >> 16) & 1u)) >> 16;   // RNE
    return (unsigned short)r;
}

__device__ __forceinline__ void gload16(const void* g, void* l) {
    __builtin_amdgcn_global_load_lds((const __attribute__((address_space(1))) void*)g,
                                     (__attribute__((address_space(3))) void*)l,
                                     16, 0, 0);
}

// --- W transpose + bf16 convert, k-window tiled --------------------------
// Wt[(k>>5)][p][k&31] = bf16(W[k][p])   (each 32-k window contiguous: 512*32)
__global__ void prep_wt_kernel(const float* __restrict__ Wn, const float* __restrict__ We,
                               unsigned short* __restrict__ Wtn, unsigned short* __restrict__ Wte)
{
    int c = blockIdx.x * 256 + threadIdx.x;      // 0 .. 2*262144-1
    const int sel = c >> 18;
    const int idx = c & 262143;
    const int p = idx >> 9, k = idx & 511;
    const float* W = sel ? We : Wn;
    unsigned short* Wt = sel ? Wte : Wtn;
    Wt[((k >> 5) << 14) + (p << 5) + (k & 31)] = f2bf(W[(size_t)k * 512 + p]);
}

// --- Qp[b][p] = sum_k question[b][k]*Wq[k][p] + bq[p] + bh[p]  (atomic k-split)
__global__ void prep_q_kernel(const float* __restrict__ question,
                              const float* __restrict__ Wnq, const float* __restrict__ bnq,
                              const float* __restrict__ bn,
                              const float* __restrict__ Weq, const float* __restrict__ beq,
                              const float* __restrict__ be,
                              float* __restrict__ Qpn, float* __restrict__ Qpe)
{
    const int b     = blockIdx.x;    // 0..63
    const int which = blockIdx.y;    // 0=n 1=e
    const int kc    = blockIdx.z;    // 0..3 (chunks of 192)
    const int p     = threadIdx.x;   // 0..511
    const float* W  = which ? Weq : Wnq;
    const float* bq = which ? beq : bnq;
    const float* bh = which ? be  : bn;
    float* Qp       = which ? Qpe : Qpn;
    const float* q  = question + b * 768;
    float s = 0.f;
    const int kbeg = kc * 192, kend = kbeg + 192;
    for (int k = kbeg; k < kend; ++k) s += q[k] * W[(size_t)k * 512 + p];
    if (kc == 0) s += bq[p] + bh[p];
    atomicAdd(&Qp[b * 512 + p], s);
}

// --- main fused kernel -------------------------------------------------------
// grid.x = M/64, 512 threads (8 waves, 2x4 wave grid). Wave (wr,wc) owns rows
// [wr*32,+32) x cols [wc*128,+128) -> acc[2][8] 16x16 frags.
__global__ __launch_bounds__(512, 1)
void fused_gemm_attn(const float* __restrict__ A,          // [M][512] fp32
                     const unsigned short* __restrict__ Bt, // [16][512][32] bf16 tiled
                     const float* __restrict__ Qp,          // [64][512] fp32 (biases folded)
                     const float* __restrict__ wv,          // [512]
                     const float* __restrict__ bvp,         // scalar
                     const int*   __restrict__ gid,         // [M]
                     float* __restrict__ eout,              // [M]  exp(s) out
                     float* __restrict__ zglob)             // [64] segment sums
{
    __shared__ float          As32[4][BM][BK];     // 32 KB, 4-deep ring, chunk-swizzled
    __shared__ unsigned short Bs[2][512][BK];      // 64 KB, double buffer, linear
    __shared__ float sred[4][BM];
    __shared__ float zpart[64];
    __shared__ int   gsh[64];

    const int tid  = threadIdx.x;
    const int wave = tid >> 6;
    const int lane = tid & 63;
    const int m16  = lane & 15;
    const int q4   = lane >> 4;
    const int wr   = wave >> 2;     // 0..1
    const int wc   = wave & 3;      // 0..3
    const long r0  = (long)blockIdx.x * BM;

    // gid -> LDS early (its compiler vmcnt(0) lands before our DMA issues,
    // keeping the hand-counted vmcnt queue exact). tid<64 == wave 0 (uniform).
    if (tid < 64) { gsh[tid] = gid[r0 + tid]; zpart[tid] = 0.f; }

    // A staging: 64 rows x 32 fp32 = 512 x 16B chunks, one DMA per thread.
    // Source chunk pre-swizzled (achk ^ (row&7)) so the linear LDS write
    // yields a bank-conflict-free swizzled layout.
    const int arow = tid >> 3;
    const int achk = tid & 7;
    const float* asrc = A + (size_t)(r0 + arow) * 512 + ((achk ^ (arow & 7)) << 2);
    // B staging: 32KB window contiguous; 4 x 16B DMA per thread, linear.
    const unsigned short* bsrc = Bt + (size_t)tid * 8;

    floatx4 acc[2][8];
#pragma unroll
    for (int i = 0; i < 2; ++i)
#pragma unroll
        for (int j = 0; j < 8; ++j) acc[i][j] = (floatx4){0.f, 0.f, 0.f, 0.f};

    // ---- prologue: B(0), A(0), A(1) in flight ----
#pragma unroll
    for (int i = 0; i < 4; ++i)
        gload16(bsrc + i * 4096, (char*)&Bs[0][0][0] + (tid + i * 512) * 16);
    gload16(asrc,      (char*)&As32[0][0][0] + tid * 16);
    gload16(asrc + 32, (char*)&As32[1][0][0] + tid * 16);

#pragma unroll
    for (int t = 0; t < NSTEP; ++t) {
        // issue next-tile DMA (stays in flight across the barrier)
        if (t + 1 < NSTEP) {
#pragma unroll
            for (int i = 0; i < 4; ++i)
                gload16(bsrc + (size_t)(t + 1) * 16384 + i * 4096,
                        (char*)&Bs[(t + 1) & 1][0][0] + (tid + i * 512) * 16);
        }
        if (t + 2 < NSTEP)
            gload16(asrc + (t + 2) * BK, (char*)&As32[(t + 2) & 3][0][0] + tid * 16);

        // drain exactly through tile t's loads; keep newer ones in flight
        if (t < NSTEP - 2)       asm volatile("s_waitcnt vmcnt(6)" ::: "memory");
        else if (t == NSTEP - 2) asm volatile("s_waitcnt vmcnt(5)" ::: "memory");
        else                     asm volatile("s_waitcnt vmcnt(0)" ::: "memory");
        __builtin_amdgcn_s_barrier();

        // A frags: fp32 from LDS (swizzled chunks), convert to bf16
        shortx8 af[2];
#pragma unroll
        for (int i = 0; i < 2; ++i) {
            const int row = wr * 32 + i * 16 + m16;
            const float* ap = &As32[t & 3][row][0];
            const float4 lo = *(const float4*)(ap + (((q4 * 2 + 0) ^ (m16 & 7)) << 2));
            const float4 hi = *(const float4*)(ap + (((q4 * 2 + 1) ^ (m16 & 7)) << 2));
            shortx8 r;
            r[0] = (short)f2bf(lo.x); r[1] = (short)f2bf(lo.y);
            r[2] = (short)f2bf(lo.z); r[3] = (short)f2bf(lo.w);
            r[4] = (short)f2bf(hi.x); r[5] = (short)f2bf(hi.y);
            r[6] = (short)f2bf(hi.z); r[7] = (short)f2bf(hi.w);
            af[i] = r;
        }
#pragma unroll
        for (int j = 0; j < 8; ++j) {
            const shortx8 bfr = *(const shortx8*)&Bs[t & 1][wc * 128 + j * 16 + m16][q4 * 8];
#pragma unroll
            for (int i = 0; i < 2; ++i)
                acc[i][j] = __builtin_amdgcn_mfma_f32_16x16x32_bf16(af[i], bfr, acc[i][j], 0, 0, 0);
        }
        __builtin_amdgcn_s_barrier();   // all reads of tile t done before restage
    }

    // ---- epilogue: s[row] = sum_p tanh(h + Qp[g][p]) * wv[p] ----
    // C/D layout: col = lane&15, row = (lane>>4)*4 + reg   [verified m89/m91]
    const float bv = bvp[0];
    float wvp[8];
#pragma unroll
    for (int j = 0; j < 8; ++j) wvp[j] = wv[wc * 128 + j * 16 + m16];

#pragma unroll
    for (int i = 0; i < 2; ++i) {
#pragma unroll
        for (int reg = 0; reg < 4; ++reg) {
            const int row = wr * 32 + i * 16 + q4 * 4 + reg;
            const int g   = gsh[row];
            const float* qrow = Qp + (size_t)g * 512 + wc * 128 + m16;
            float partial = 0.f;
#pragma unroll
            for (int j = 0; j < 8; ++j) {
                float h  = acc[i][j][reg] + qrow[j * 16];
                float ex = __expf(2.f * h);                                // tanh
                float tt = (ex - 1.f) * __builtin_amdgcn_rcpf(ex + 1.f);
                partial += tt * wvp[j];
            }
            partial += __shfl_xor(partial, 1);
            partial += __shfl_xor(partial, 2);
            partial += __shfl_xor(partial, 4);
            partial += __shfl_xor(partial, 8);
            if (m16 == 0) sred[wc][row] = partial;   // per-colblock partial
        }
    }
    __syncthreads();
    if (tid < BM) {
        float s = bv + sred[0][tid] + sred[1][tid] + sred[2][tid] + sred[3][tid];
        float e = __expf(s);                       // no max-subtract: |s| small
        eout[r0 + tid] = e;
        atomicAdd(&zpart[gsh[tid]], e);
    }
    __syncthreads();
    if (tid < 64) {
        float v = zpart[tid];
        if (v != 0.f) atomicAdd(&zglob[tid], v);
    }
}

// --- normalize: att = e / z[gid] --------------------------------------------
__global__ void norm_kernel(float* __restrict__ out, const int* __restrict__ ngid,
                            const int* __restrict__ egid, const float* __restrict__ z)
{
    int idx = blockIdx.x * 256 + threadIdx.x;     // 0..393215
    float zz;
    if (idx < TN_CONST) zz = z[ngid[idx]];
    else                zz = z[64 + egid[idx - TN_CONST]];
    out[idx] = out[idx] / zz;
}

extern "C" void kernel_launch(void* const* d_in, const int* in_sizes, int n_in,
                              void* d_out, int out_size, void* d_ws, size_t ws_size,
                              hipStream_t stream)
{
    const float* question = (const float*)d_in[0];
    const float* nodes    = (const float*)d_in[1];
    const float* edges    = (const float*)d_in[2];
    const float* W_nq     = (const float*)d_in[3];
    const float* b_nq     = (const float*)d_in[4];
    const float* W_n      = (const float*)d_in[5];
    const float* b_n      = (const float*)d_in[6];
    const float* w_nv     = (const float*)d_in[7];
    const float* b_nv     = (const float*)d_in[8];
    const float* W_eq     = (const float*)d_in[9];
    const float* b_eq     = (const float*)d_in[10];
    const float* W_e      = (const float*)d_in[11];
    const float* b_e      = (const float*)d_in[12];
    const float* w_ev     = (const float*)d_in[13];
    const float* b_ev     = (const float*)d_in[14];
    const int* node_gid   = (const int*)d_in[15];
    const int* edge_gid   = (const int*)d_in[16];
    float* out = (float*)d_out;

    // workspace layout (bytes):
    //   [0,512)              z[128]
    //   [512,131584)         Qpn [64*512] f32
    //   [131584,262656)      Qpe [64*512] f32
    //   [262656,786944)      Wtn [512*512] bf16 (tiled)
    //   [786944,1311232)     Wte [512*512] bf16 (tiled)
    char* ws = (char*)d_ws;
    float*          z   = (float*)(ws);
    float*          Qpn = (float*)(ws + 512);
    float*          Qpe = (float*)(ws + 131584);
    unsigned short* Wtn = (unsigned short*)(ws + 262656);
    unsigned short* Wte = (unsigned short*)(ws + 786944);

    hipMemsetAsync(ws, 0, 262656, stream);  // z + Qpn + Qpe

    prep_wt_kernel<<<2048, 256, 0, stream>>>(W_n, W_e, Wtn, Wte);
    prep_q_kernel<<<dim3(64, 2, 4), 512, 0, stream>>>(question, W_nq, b_nq, b_n,
                                                      W_eq, b_eq, b_e, Qpn, Qpe);
    fused_gemm_attn<<<TN_CONST / BM, 512, 0, stream>>>(nodes, Wtn, Qpn, w_nv, b_nv,
                                                       node_gid, out, z);
    fused_gemm_attn<<<TE_CONST / BM, 512, 0, stream>>>(edges, Wte, Qpe, w_ev, b_ev,
                                                       edge_gid, out + TN_CONST, z + 64);
    norm_kernel<<<1536, 256, 0, stream>>>(out, node_gid, edge_gid, z);
}